// Round 9
// baseline (208.876 us; speedup 1.0000x reference)
//
#include <hip/hip_runtime.h>

#define EPSB 1e-5f

typedef __attribute__((ext_vector_type(8))) short bf16x8;
typedef __attribute__((ext_vector_type(4))) float f32x4;

__device__ __forceinline__ unsigned short f2b(float f) {
  union { float f; unsigned u; } cv; cv.f = f;
  unsigned r = cv.u + 0x7FFFu + ((cv.u >> 16) & 1u);
  return (unsigned short)(r >> 16);
}
__device__ __forceinline__ float b2f(unsigned short v) {
  union { unsigned u; float f; } cv; cv.u = ((unsigned)v) << 16;
  return cv.f;
}

// ============ L1: MFMA compress (+BN+ReLU) | weight conversions | border zeros ======
__global__ __launch_bounds__(256) void k_compress(
    const float* __restrict__ x, const float* __restrict__ cw,
    const float* __restrict__ g1, const float* __restrict__ b1,
    const float* __restrict__ m1, const float* __restrict__ v1,
    const float* __restrict__ k1w, const float* __restrict__ k2w,
    const float* __restrict__ pw,
    unsigned short* __restrict__ comp_t, unsigned short* __restrict__ pwb,
    unsigned short* __restrict__ wt1, unsigned short* __restrict__ wt2) {
  int bid = blockIdx.x, t = threadIdx.x;
  if (bid >= 96) {
    int u = (bid - 96) * 256 + t;
    if (u < 65536) {
      pwb[u] = f2b(pw[u]);
    } else if (u < 102400) {
      int a = u - 65536;
      int co = a / 576, k = a % 576, tap = k >> 6, ci = k & 63;
      wt1[a] = f2b(k1w[co * 576 + ci * 9 + tap]);
    } else if (u < 176128) {
      int c2 = u - 102400;
      int co = c2 / 576, k = c2 % 576, tap = k >> 6, ci = k & 63;
      wt2[c2] = (co < 100) ? f2b(k2w[co * 576 + ci * 9 + tap]) : (unsigned short)0;
    } else {
      int v = u - 176128;
      if (v < 25600) {
        int n = v / 12800, r = v % 12800;
        int bp = r >> 5, c32 = r & 31;
        int rr, cc;
        if (bp < 104) { rr = bp / 52; cc = bp % 52; }
        else if (bp >= 296) { rr = 50 + (bp - 296) / 52; cc = (bp - 296) % 52; }
        else { int q = bp - 104; rr = 2 + (q >> 2); int c4 = q & 3; cc = (c4 < 2) ? c4 : c4 + 48; }
        ((unsigned*)comp_t)[((size_t)n * 2704 + rr * 52 + cc) * 32 + c32] = 0u;
      }
    }
    return;
  }
  // ---- MFMA compress: per (n,y) row  comp[64 co][48 px] = W[64x256] @ X[256][48]
  __shared__ __align__(16) unsigned short wlds[16384];   // W [co][256 ci], XOR by co
  __shared__ __align__(16) unsigned short xlds[12288];   // X [px][256 ci], XOR by px
  int n = bid / 48, y = bid % 48;
  for (int f = t; f < 16384; f += 256) {
    int co = f >> 8;
    int ba = (f * 2) ^ ((co & 7) << 4);
    *(unsigned short*)((char*)wlds + ba) = f2b(cw[f]);
  }
  const float* xrow = x + (size_t)n * 256 * 2304 + y * 48;
  for (int f = t; f < 12288; f += 256) {
    int ci = f / 48, px = f - ci * 48;
    int ba = ((px * 256 + ci) * 2) ^ ((px & 7) << 4);
    *(unsigned short*)((char*)xlds + ba) = f2b(xrow[(size_t)ci * 2304 + px]);
  }
  __syncthreads();
  int wid = t >> 6, l = t & 63, l15 = l & 15, lg = l >> 4;
  f32x4 acc[3];
  acc[0] = acc[1] = acc[2] = (f32x4){0.f, 0.f, 0.f, 0.f};
  int coA = wid * 16 + l15;
#pragma unroll
  for (int kbi = 0; kbi < 8; ++kbi) {
    int col = kbi * 32 + lg * 8;
    bf16x8 afr = *(const bf16x8*)((char*)wlds + (((coA * 256 + col) * 2) ^ ((coA & 7) << 4)));
#pragma unroll
    for (int nt = 0; nt < 3; ++nt) {
      int px = nt * 16 + l15;
      bf16x8 bfr = *(const bf16x8*)((char*)xlds + (((px * 256 + col) * 2) ^ ((px & 7) << 4)));
      acc[nt] = __builtin_amdgcn_mfma_f32_16x16x32_bf16(afr, bfr, acc[nt], 0, 0, 0);
    }
  }
  int co0 = wid * 16 + lg * 4;
  float s0 = g1[co0] / sqrtf(v1[co0] + EPSB);
  float s1 = g1[co0 + 1] / sqrtf(v1[co0 + 1] + EPSB);
  float s2 = g1[co0 + 2] / sqrtf(v1[co0 + 2] + EPSB);
  float s3 = g1[co0 + 3] / sqrtf(v1[co0 + 3] + EPSB);
  float d0 = b1[co0] - m1[co0] * s0;
  float d1 = b1[co0 + 1] - m1[co0 + 1] * s1;
  float d2 = b1[co0 + 2] - m1[co0 + 2] * s2;
  float d3 = b1[co0 + 3] - m1[co0 + 3] * s3;
  unsigned short* dst = comp_t + ((size_t)n * 2704 + (y + 2) * 52) * 64;
#pragma unroll
  for (int nt = 0; nt < 3; ++nt) {
    int px = nt * 16 + l15;
    ushort4 pk;
    pk.x = f2b(fmaxf(fmaf(acc[nt][0], s0, d0), 0.f));
    pk.y = f2b(fmaxf(fmaf(acc[nt][1], s1, d1), 0.f));
    pk.z = f2b(fmaxf(fmaf(acc[nt][2], s2, d2), 0.f));
    pk.w = f2b(fmaxf(fmaf(acc[nt][3], s3, d3), 0.f));
    *(ushort4*)&dst[(px + 2) * 64 + co0] = pk;
  }
}

// ============ L2: mega — ke1+ke2 (halo) + softmax/bilinear/fold + reassembly + proj =
__global__ __launch_bounds__(512, 4) void k_mega(
    const float* __restrict__ x, const unsigned short* __restrict__ comp_t,
    const unsigned short* __restrict__ wt1, const unsigned short* __restrict__ wt2,
    const unsigned short* __restrict__ pwb,
    const float* __restrict__ gk, const float* __restrict__ bk,
    const float* __restrict__ mk, const float* __restrict__ vk,
    const float* __restrict__ g2, const float* __restrict__ b2,
    const float* __restrict__ m2, const float* __restrict__ v2,
    float* __restrict__ out) {
  __shared__ __align__(16) char smem[66752];
  unsigned short* xls_b = (unsigned short*)smem;          // 256 slots x 37  (18944 B)
  float* w9s   = (float*)(smem + 18944);                  // 1152 f (4608 B)
  float* sb2s  = (float*)(smem + 23552);                  // 512 f  (2048 B)
  float* sbk   = (float*)(smem + 25600);                  // 128 f  (512 B)
  char*  comp_sB = smem + 26112;                          // 9x16x64 bf16 (18432 B)
  char*  k1_sB   = smem + 44544;                          // 61x64 bf16 (7808 B)
  float* kern_s  = (float*)(smem + 52352);                // 31x116 f32 (14384 B)
  unsigned short* finT = (unsigned short*)(smem + 26112); // 64x256 bf16 alias (32768 B)

  int blk = blockIdx.x;                                   // 576 = 2*48*6
  int n = blk / 288, r = blk % 288;
  int y48 = r / 6, xt = r % 6;
  int X0 = xt * 32, x480 = xt * 8;
  int t = threadIdx.x;
  int wv = t >> 6, l = t & 63, l15 = l & 15, lg = l >> 4;

  // ---- stage: BN coeffs, comp window, x window ----
  if (t < 256) {
    float iv = g2[t] / sqrtf(v2[t] + EPSB);
    sb2s[t] = iv; sb2s[256 + t] = b2[t] - m2[t] * iv;
  } else if (t < 320) {
    int c = t - 256;
    float iv = gk[c] / sqrtf(vk[c] + EPSB);
    sbk[c] = iv; sbk[64 + c] = bk[c] - mk[c] * iv;
  }
  for (int f = t; f < 1152; f += 512) {                   // comp_s: rows y48-4..+4, cols x480-4..+11
    int ci0 = (f & 7) * 8;
    int g = f >> 3;
    int cc = g & 15, rr = g >> 4;
    int pr = y48 - 2 + rr;                                // padded row index in comp_t
    int pc = x480 - 2 + cc;
    bf16x8 vv = (bf16x8){0, 0, 0, 0, 0, 0, 0, 0};
    if ((unsigned)pr < 52u && (unsigned)pc < 52u)
      vv = *(const bf16x8*)&comp_t[(((size_t)n * 52 + pr) * 52 + pc) * 64 + ci0];
    int ba = ((rr * 16 + cc) * 64 + ci0) * 2 ^ ((cc & 7) << 4);
    *(bf16x8*)(comp_sB + ba) = vv;
  }
  const float* xb = x + (size_t)n * 256 * 2304;
  for (int f = t; f < 8448; f += 512) {                   // x window, bf16
    int c = f / 33, rc = f - c * 33;
    int ry = rc / 11, cx = rc - ry * 11;
    int sy = min(max(y48 + ry - 1, 0), 47);
    int sx = min(max(x480 + cx - 1, 0), 47);
    int slot = (c & 3) * 64 + (c >> 2);
    xls_b[slot * 37 + rc] = f2b(xb[(size_t)c * 2304 + sy * 48 + sx]);
  }
  __syncthreads();

  // ---- ke1 (halo): k1[5 rows x 12 cols x 64 co] from comp_s ----
  for (int tk = wv; tk < 16; tk += 8) {
    int cotile = tk >> 2, pxtile = tk & 3;
    int p = pxtile * 16 + l15;
    int pcr = min(p, 59);
    int rowp = pcr / 12, colp = pcr - rowp * 12;
    f32x4 acc = (f32x4){0.f, 0.f, 0.f, 0.f};
    const unsigned short* arow = wt1 + (size_t)(cotile * 16 + l15) * 576;
#pragma unroll
    for (int kbi = 0; kbi < 18; ++kbi) {
      int tap = kbi >> 1;
      int ky = tap / 3, kx = tap % 3;
      int ci0 = (kbi & 1) * 32 + lg * 8;
      bf16x8 afr = *(const bf16x8*)&arow[kbi * 32 + lg * 8];
      int crow = rowp + 2 * ky, ccol = colp + 2 * kx;
      int ba = ((crow * 16 + ccol) * 64 + ci0) * 2 ^ ((ccol & 7) << 4);
      bf16x8 bfr = *(const bf16x8*)(comp_sB + ba);
      acc = __builtin_amdgcn_mfma_f32_16x16x32_bf16(afr, bfr, acc, 0, 0, 0);
    }
    int co0 = cotile * 16 + lg * 4;
    bool valid = (p < 60) && ((unsigned)(y48 - 2 + rowp) < 48u) && ((unsigned)(x480 - 2 + colp) < 48u);
    int wslot = min(p, 60);
    ushort4 pk;
    pk.x = valid ? f2b(fmaxf(fmaf(acc[0], sbk[co0], sbk[64 + co0]), 0.f)) : (unsigned short)0;
    pk.y = valid ? f2b(fmaxf(fmaf(acc[1], sbk[co0 + 1], sbk[64 + co0 + 1]), 0.f)) : (unsigned short)0;
    pk.z = valid ? f2b(fmaxf(fmaf(acc[2], sbk[co0 + 2], sbk[64 + co0 + 2]), 0.f)) : (unsigned short)0;
    pk.w = valid ? f2b(fmaxf(fmaf(acc[3], sbk[co0 + 3], sbk[64 + co0 + 3]), 0.f)) : (unsigned short)0;
    *(ushort4*)(k1_sB + (((wslot * 64 + co0) * 2) ^ ((wslot & 7) << 4))) = pk;
  }
  __syncthreads();

  // ---- ke2 (halo): kern[3 slots x 10 cols x 112 co] from k1_s ----
  for (int tk = wv; tk < 14; tk += 8) {
    int cotile = tk % 7, pxtile = tk / 7;
    int p = pxtile * 16 + l15;
    int pcr = min(p, 29);
    int s = pcr / 10, cx = pcr - s * 10;
    int gr = min(max(y48 - 1 + s, 0), 47);
    int gc = min(max(x480 - 1 + cx, 0), 47);
    int lrb = gr - y48 + 1, lcb = gc - x480 + 1;
    f32x4 acc = (f32x4){0.f, 0.f, 0.f, 0.f};
    const unsigned short* arow = wt2 + (size_t)(cotile * 16 + l15) * 576;
#pragma unroll
    for (int kbi = 0; kbi < 18; ++kbi) {
      int tap = kbi >> 1;
      int ky = tap / 3, kx = tap % 3;
      int ci0 = (kbi & 1) * 32 + lg * 8;
      bf16x8 afr = *(const bf16x8*)&arow[kbi * 32 + lg * 8];
      int pk1 = (lrb + ky) * 12 + (lcb + kx);
      int ba = ((pk1 * 64 + ci0) * 2) ^ ((pk1 & 7) << 4);
      bf16x8 bfr = *(const bf16x8*)(k1_sB + ba);
      acc = __builtin_amdgcn_mfma_f32_16x16x32_bf16(afr, bfr, acc, 0, 0, 0);
    }
    int co0 = cotile * 16 + lg * 4;
    int wslot = min(p, 30);
    float4 vv = {acc[0], acc[1], acc[2], acc[3]};
    *(float4*)&kern_s[wslot * 116 + co0] = vv;
  }
  __syncthreads();

  // ---- softmax + bilinear + fold -> w9s ----
  {
    int s = t & 3, tri = t >> 2;
    int u = tri & 3, w2l = (tri >> 2) & 15, yhh = tri >> 6;
    int y96 = 2 * y48 + yhh;
    int w2 = xt * 16 + w2l;
    float syf = fminf(fmaxf(y96 * 0.5f - 0.25f, 0.f), 47.f);
    int y0 = (int)syf; float wy = syf - (float)y0; int y1 = min(y0 + 1, 47);
    float sxf = fminf(fmaxf(w2 * 0.5f - 0.25f, 0.f), 47.f);
    int x0 = (int)sxf; float wx = sxf - (float)x0; int x1 = min(x0 + 1, 47);
    int slr = ((s & 2) ? y1 : y0) - y48 + 1;
    int cxr = ((s & 1) ? x1 : x0) - x480 + 1;
    float wgt = ((s & 1) ? wx : 1.f - wx) * ((s & 2) ? wy : 1.f - wy);
    const float* p = &kern_s[(slr * 10 + cxr) * 116 + u * 25];
    float bl[25], mx = -3.4e38f;
#pragma unroll
    for (int k = 0; k < 25; ++k) { bl[k] = p[k]; mx = fmaxf(mx, bl[k]); }
    float sum = 0.f;
#pragma unroll
    for (int k = 0; k < 25; ++k) { bl[k] = __expf(bl[k] - mx); sum += bl[k]; }
    float rs = wgt / sum;
#pragma unroll
    for (int k = 0; k < 25; ++k) {
      bl[k] *= rs;
      bl[k] += __shfl_xor(bl[k], 1);
      bl[k] += __shfl_xor(bl[k], 2);
    }
    if (s == 0) {
#pragma unroll
      for (int kh = 0; kh < 5; ++kh) {
        bool vy = (unsigned)(y96 + kh - 2) < 96u;
#pragma unroll
        for (int kw = 0; kw < 5; ++kw) {
          bool vx = (unsigned)(w2 + kw - 2) < 96u;
          if (!(vy && vx)) bl[kh * 5 + kw] = 0.f;
        }
      }
      int py = yhh, px_ = w2l & 1;
      float cc0[5], cc1[5], cc2[5];
#pragma unroll
      for (int kh = 0; kh < 5; ++kh) {
        cc0[kh] = px_ ? bl[kh * 5 + 0] : bl[kh * 5 + 0] + bl[kh * 5 + 1];
        cc1[kh] = px_ ? bl[kh * 5 + 1] + bl[kh * 5 + 2] : bl[kh * 5 + 2] + bl[kh * 5 + 3];
        cc2[kh] = px_ ? bl[kh * 5 + 3] + bl[kh * 5 + 4] : bl[kh * 5 + 4];
      }
      float* op = &w9s[(yhh * 16 + w2l) * 36 + u * 9];
      op[0] = py ? cc0[0] : cc0[0] + cc0[1];
      op[1] = py ? cc1[0] : cc1[0] + cc1[1];
      op[2] = py ? cc2[0] : cc2[0] + cc2[1];
      op[3] = py ? cc0[1] + cc0[2] : cc0[2] + cc0[3];
      op[4] = py ? cc1[1] + cc1[2] : cc1[2] + cc1[3];
      op[5] = py ? cc2[1] + cc2[2] : cc2[2] + cc2[3];
      op[6] = py ? cc0[3] + cc0[4] : cc0[4];
      op[7] = py ? cc1[3] + cc1[4] : cc1[4];
      op[8] = py ? cc2[3] + cc2[4] : cc2[4];
    }
  }
  __syncthreads();   // w9s ready; comp_s/k1_s/kern_s dead -> finT may alias

  int ci = t & 255, rY = t >> 8;
  int u = ci >> 6, ch = ci & 63;
  int cb = ci >> 3, crr = ci & 7;
  const unsigned short* a0p = pwb + (size_t)(wv * 32 + l15) * 256;
  const unsigned short* a1p = a0p + 16 * 256;
  size_t outn = (size_t)n * 256 * 36864;
  int Ybase = 4 * y48;

#pragma unroll
  for (int c = 0; c < 2; ++c) {
    // ---- phase 1: 9-tap reassembly (x in bf16) -> finT ----
    {
      const unsigned short* xc0 = &xls_b[((rY * 2 + 0) * 64 + ch) * 37];
      const unsigned short* xc1 = &xls_b[((rY * 2 + 1) * 64 + ch) * 37];
      float xw0[9], xw1[9];
#pragma unroll
      for (int ry = 0; ry < 3; ++ry)
#pragma unroll
        for (int cx = 0; cx < 3; ++cx) {
          xw0[ry * 3 + cx] = b2f(xc0[ry * 11 + cx]);
          xw1[ry * 3 + cx] = b2f(xc1[ry * 11 + cx]);
        }
#pragma unroll
      for (int j = 0; j < 16; ++j) {
        if (j >= 2 && (j & 1) == 0) {
          int nc = (j >> 1) + 2;
#pragma unroll
          for (int ry = 0; ry < 3; ++ry) {
            xw0[ry*3+0]=xw0[ry*3+1]; xw0[ry*3+1]=xw0[ry*3+2]; xw0[ry*3+2]=b2f(xc0[ry*11+nc]);
            xw1[ry*3+0]=xw1[ry*3+1]; xw1[ry*3+1]=xw1[ry*3+2]; xw1[ry*3+2]=b2f(xc1[ry*11+nc]);
          }
        }
        const float* wt = &w9s[(c * 16 + j) * 36 + u * 9];
        float a0 = 0.f, a1 = 0.f;
#pragma unroll
        for (int k9 = 0; k9 < 9; ++k9) {
          float wvv = wt[k9];
          a0 = fmaf(xw0[k9], wvv, a0);
          a1 = fmaf(xw1[k9], wvv, a1);
        }
        int px0 = rY * 32 + 2 * j, px1 = px0 + 1;
        finT[px0 * 256 + ((cb ^ (px0 & 7)) * 8 + crr)] = f2b(a0);
        finT[px1 * 256 + ((cb ^ (px1 & 7)) * 8 + crr)] = f2b(a1);
      }
    }
    __syncthreads();

    // ---- phase 2: MFMA  C[256 o][64 px] = pwb @ finT ----
    f32x4 acc[2][4];
#pragma unroll
    for (int mi = 0; mi < 2; ++mi)
#pragma unroll
      for (int nt = 0; nt < 4; ++nt) acc[mi][nt] = (f32x4){0.f, 0.f, 0.f, 0.f};
#pragma unroll
    for (int kbi = 0; kbi < 8; ++kbi) {
      bf16x8 afr0 = *(const bf16x8*)&a0p[kbi * 32 + lg * 8];
      bf16x8 afr1 = *(const bf16x8*)&a1p[kbi * 32 + lg * 8];
      int cbk = kbi * 4 + lg;
#pragma unroll
      for (int nt = 0; nt < 4; ++nt) {
        int row = nt * 16 + l15;
        bf16x8 bfr = *(const bf16x8*)&finT[row * 256 + ((cbk ^ (row & 7)) * 8)];
        acc[0][nt] = __builtin_amdgcn_mfma_f32_16x16x32_bf16(afr0, bfr, acc[0][nt], 0, 0, 0);
        acc[1][nt] = __builtin_amdgcn_mfma_f32_16x16x32_bf16(afr1, bfr, acc[1][nt], 0, 0, 0);
      }
    }
#pragma unroll
    for (int mi = 0; mi < 2; ++mi) {
#pragma unroll
      for (int r4 = 0; r4 < 4; ++r4) {
        int o = (wv * 2 + mi) * 16 + lg * 4 + r4;
        float sc = sb2s[o], bi = sb2s[256 + o];
#pragma unroll
        for (int nt = 0; nt < 4; ++nt) {
          int px = nt * 16 + l15;
          int Yl = c * 2 + (px >> 5), Xl = px & 31;
          float val = fmaxf(fmaf(acc[mi][nt][r4], sc, bi), 0.f);
          out[outn + (size_t)o * 36864 + (size_t)(Ybase + Yl) * 192 + X0 + Xl] = val;
        }
      }
    }
    if (c == 0) __syncthreads();
  }
}

extern "C" void kernel_launch(void* const* d_in, const int* in_sizes, int n_in,
                              void* d_out, int out_size, void* d_ws, size_t ws_size,
                              hipStream_t stream) {
  const float* x   = (const float*)d_in[0];
  const float* cw  = (const float*)d_in[1];
  const float* g1  = (const float*)d_in[2];
  const float* b1  = (const float*)d_in[3];
  const float* m1  = (const float*)d_in[4];
  const float* v1  = (const float*)d_in[5];
  const float* k1w = (const float*)d_in[6];
  const float* gk  = (const float*)d_in[7];
  const float* bk  = (const float*)d_in[8];
  const float* mk  = (const float*)d_in[9];
  const float* vk  = (const float*)d_in[10];
  const float* k2w = (const float*)d_in[11];
  const float* pw  = (const float*)d_in[12];
  const float* g2  = (const float*)d_in[13];
  const float* b2  = (const float*)d_in[14];
  const float* m2  = (const float*)d_in[15];
  const float* v2  = (const float*)d_in[16];
  float* out = (float*)d_out;
  float* ws  = (float*)d_ws;

  unsigned short* comp_t = (unsigned short*)ws;            // 346112 bf16
  unsigned short* pwb = (unsigned short*)(ws + 173056);    // 65536 bf16
  unsigned short* wt1 = (unsigned short*)(ws + 205824);    // 36864 bf16
  unsigned short* wt2 = (unsigned short*)(ws + 224256);    // 73728 bf16

  k_compress<<<884, 256, 0, stream>>>(x, cw, g1, b1, m1, v1, k1w, k2w, pw,
                                      comp_t, pwb, wt1, wt2);
  k_mega<<<576, 512, 0, stream>>>(x, comp_t, wt1, wt2, pwb,
                                  gk, bk, mk, vk, g2, b2, m2, v2, out);
}